// Round 10
// baseline (259.027 us; speedup 1.0000x reference)
//
#include <hip/hip_runtime.h>

// ---------------------------------------------------------------------------
// SAGE 3-layer GNN.  (R17 = R16 + atomic-free agg partial planes + ushort es)
//   Per layer: S = X@W_self + b (fp32) ; P = X@W_neigh (bf16 row-major)
//              h[i] = act( S[i] + (sum_{j in N_in(i)} P[j]) / max(deg_i,1) )
//
// Evidence log:
//   R0..R5: random row-gather agg ~150us = per-CU gather service wall.
//   R8 FAILED: dim-sliced LDS planes (32x edge visits).
//   R9 WIN: src-bucket LDS slicing + coalesced 256B Hn atomics.
//   R10 WIN: finish via sorted-graph_id register accumulation.
//   R11 WIN: one-pass fixed-cap CSR build. 255.9us.
//   R12/R13/R14: persistent-kernel route FAILED (capture kill; L2-inval
//     spin storm; structurally higher traffic floor). Reverted.
//   R15 WIN (249.1): build fused into gemm1; readout ticket-fused into finish.
//   R16 WIN (232.5): split-K wave-group GEMMs (2 waves/SIMD). gemm1_build
//     left top-5 (<41us). Fill (43us, 268MB harness re-poison) is INSIDE
//     dur_us (R13 accounting: 821+43+gaps=876) -> immovable floor tax.
//     Budget: ~190us mine; aggs ~32us EACH (~95 total) = biggest block.
//   R17 (this round): aggs are modeled atomic-bound: 80000 x 256B
//     device-scope fp32 RMW/agg serialize at the coherence point (L2s
//     non-coherent). Each (dst,bucket) row has ONE writer -> plain-store
//     per-bucket partials Hn_part[key][64]; consumers (gemm2/3 loader,
//     finish) sum 8 partials guarded by cnt8[key]>0 (no zeroing needed;
//     gemm epilogues drop Hn-zero stores). es -> ushort LOCAL idx (64B/row).
//   Predicted: agg 32 -> 15-18 each, total 232.5 -> ~195-210.
//   Fallback: if flat, atomics were cheap -> next: 2-rows-per-wave gather.
// ---------------------------------------------------------------------------

#define DH 64
#define NG 16
#define NSB 8        // src buckets
#define DTILES 32    // dst tiles -> grid 8*32 = 256 agg blocks (1/CU)
#define MAXNPB 1250  // max nodes per bucket (M <= 10000)
#define CAP 32       // edge slots per (dst,bucket) row; Poisson(4) tail ~1e-19
#define TILE_F 4352  // 64*68 floats per LDS tile

__device__ __forceinline__ unsigned short f2bf(float f) {
    unsigned int u = __float_as_uint(f);
    unsigned int r = (u + 0x7FFFu + ((u >> 16) & 1u)) >> 16;   // RNE
    return (unsigned short)r;
}
__device__ __forceinline__ float bfu(unsigned short v) {
    return __uint_as_float(((unsigned int)v) << 16);
}

// ---- fused: layer-1 dual GEMM (blocks [0,gb)) + CSR build ([gb,gb+eb)) ----
// gemm: split-K wave groups (R16-proven). build: one edge per thread,
// p=atomicAdd(cnt8[key]); es16[key*CAP+p] = LOCAL src idx (ushort).
__global__ __launch_bounds__(512) void gemm1_build_kernel(
    const float* __restrict__ X, const float* __restrict__ Ws_g,
    const float* __restrict__ Wn_g, const float* __restrict__ bias,
    float* __restrict__ S, unsigned short* __restrict__ P,
    const int* __restrict__ src, const int* __restrict__ dst,
    int* __restrict__ cnt8, unsigned short* __restrict__ es16,
    int M, int E, int npb8, int gb) {
    constexpr int K = 256;
    int tid = threadIdx.x;

    if ((int)blockIdx.x >= gb) {          // ---- build part ----
        int i = ((int)blockIdx.x - gb) * 512 + tid;
        if (i < E) {
            int s = src[i];
            int b = s / npb8;
            int k = dst[i] * NSB + b;
            int p = atomicAdd(&cnt8[k], 1);
            if (p < CAP)                   // clamp: memory-safe
                es16[(size_t)k * CAP + p] = (unsigned short)(s - b * npb8);
        }
        return;
    }

    // ---- gemm part: split-K over 2 wave groups (R16-proven) ----
    __shared__ float smem[6 * TILE_F];    // grp0: Xs,Ws,Wn ; grp1: Xs,Ws,Wn
    const int grp = tid >> 8;             // 0: waves 0-3, 1: waves 4-7
    const int t   = tid & 255;
    const int cx = t & 15;
    const int ry = t >> 4;
    float* Xs  = smem + grp * 3 * TILE_F;
    float* Wsm = Xs + TILE_F;
    float* Wnm = Wsm + TILE_F;
    const int row0 = blockIdx.x * 64;
    float acc_s[4][4] = {{0.f}};
    float acc_n[4][4] = {{0.f}};

    for (int st = 0; st < 2; ++st) {
        const int kc = grp * 128 + st * 64;
#pragma unroll
        for (int it = 0; it < 4; ++it) {
            int q = t + 256 * it;         // 0..1023
            int row = q >> 4;
            int k4 = (q & 15) * 4;
            float4 xv = make_float4(0.f, 0.f, 0.f, 0.f);
            int gr = row0 + row;
            if (gr < M)
                xv = *reinterpret_cast<const float4*>(&X[(size_t)gr * K + kc + k4]);
            *reinterpret_cast<float4*>(&Xs[row * 68 + k4]) = xv;
            *reinterpret_cast<float4*>(&Wsm[row * 68 + k4]) =
                *reinterpret_cast<const float4*>(&Ws_g[(size_t)(kc + row) * 64 + k4]);
            *reinterpret_cast<float4*>(&Wnm[row * 68 + k4]) =
                *reinterpret_cast<const float4*>(&Wn_g[(size_t)(kc + row) * 64 + k4]);
        }
        __syncthreads();
#pragma unroll 4
        for (int kk = 0; kk < 64; ++kk) {
            float av[4], bs[4], bn[4];
#pragma unroll
            for (int j = 0; j < 4; ++j) av[j] = Xs[(ry * 4 + j) * 68 + kk];
#pragma unroll
            for (int i = 0; i < 4; ++i) {
                bs[i] = Wsm[kk * 68 + cx + 16 * i];
                bn[i] = Wnm[kk * 68 + cx + 16 * i];
            }
#pragma unroll
            for (int j = 0; j < 4; ++j)
#pragma unroll
                for (int i = 0; i < 4; ++i) {
                    acc_s[j][i] += av[j] * bs[i];
                    acc_n[j][i] += av[j] * bn[i];
                }
        }
        __syncthreads();
    }

    // combine: grp1 -> its own (dead) LDS region, stride 33 (bank-free)
    float* flat = smem + 3 * TILE_F;
    if (grp == 1) {
        int o = t * 33;
#pragma unroll
        for (int j = 0; j < 4; ++j)
#pragma unroll
            for (int i = 0; i < 4; ++i) {
                flat[o + j * 4 + i]      = acc_s[j][i];
                flat[o + 16 + j * 4 + i] = acc_n[j][i];
            }
    }
    __syncthreads();
    if (grp == 0) {
        int o = t * 33;
#pragma unroll
        for (int j = 0; j < 4; ++j)
#pragma unroll
            for (int i = 0; i < 4; ++i) {
                acc_s[j][i] += flat[o + j * 4 + i];
                acc_n[j][i] += flat[o + 16 + j * 4 + i];
            }
#pragma unroll
        for (int j = 0; j < 4; ++j) {
            int r = row0 + ry * 4 + j;
            if (r < M) {
#pragma unroll
                for (int i = 0; i < 4; ++i) {
                    int col = cx + 16 * i;
                    S[(size_t)r * DH + col] = acc_s[j][i] + bias[col];
                    P[(size_t)r * DH + col] = f2bf(acc_n[j][i]);
                }
            }
        }
    }
}

// ---- dual GEMM layers 2/3 (K=64): X = relu(S + sum(partials)/deg) ---------
// 512 threads, split-kk wave groups (R16). Loader sums the 8 per-bucket
// partial planes guarded by cnt8[key]>0 (stale planes skipped, no zeroing).
__global__ __launch_bounds__(512) void gemm_dual_kernel(
    const float* __restrict__ X, const float* __restrict__ Ws_g,
    const float* __restrict__ Wn_g, const float* __restrict__ bias,
    const float* __restrict__ Hn_part, const int* __restrict__ cnt8,
    float* __restrict__ S, unsigned short* __restrict__ P, int M) {
    constexpr int K = 64;
    __shared__ float smem[3 * TILE_F];    // Xs, Ws, Wn (combine reuses base)
    int tid = threadIdx.x;
    const int grp = tid >> 8;
    const int t   = tid & 255;
    const int cx = t & 15;
    const int ry = t >> 4;
    float* Xs  = smem;
    float* Wsm = smem + TILE_F;
    float* Wnm = smem + 2 * TILE_F;
    const int row0 = blockIdx.x * 64;
    float acc_s[4][4] = {{0.f}};
    float acc_n[4][4] = {{0.f}};

    {   // stage by all 512 threads (2 passes cover 64 rows x 16 k4-groups)
#pragma unroll
        for (int it = 0; it < 2; ++it) {
            int q = tid + 512 * it;       // 0..1023
            int row = q >> 4;
            int k4 = (q & 15) * 4;
            float4 xv = make_float4(0.f, 0.f, 0.f, 0.f);
            int gr = row0 + row;
            if (gr < M) {
                xv = *reinterpret_cast<const float4*>(&X[(size_t)gr * K + k4]);
                const int4* cp = reinterpret_cast<const int4*>(&cnt8[gr * NSB]);
                int4 c0 = cp[0], c1 = cp[1];
                int ca[8] = {c0.x, c0.y, c0.z, c0.w, c1.x, c1.y, c1.z, c1.w};
                int deg = ca[0] + ca[1] + ca[2] + ca[3] +
                          ca[4] + ca[5] + ca[6] + ca[7];
                float4 hv = make_float4(0.f, 0.f, 0.f, 0.f);
                size_t pb = (size_t)gr * NSB * DH + k4;
#pragma unroll
                for (int b = 0; b < NSB; ++b) {
                    if (ca[b] > 0) {
                        float4 pv = *reinterpret_cast<const float4*>(&Hn_part[pb + b * DH]);
                        hv.x += pv.x; hv.y += pv.y; hv.z += pv.z; hv.w += pv.w;
                    }
                }
                float inv = 1.f / fmaxf((float)deg, 1.f);
                xv.x = fmaxf(fmaf(hv.x, inv, xv.x), 0.f);
                xv.y = fmaxf(fmaf(hv.y, inv, xv.y), 0.f);
                xv.z = fmaxf(fmaf(hv.z, inv, xv.z), 0.f);
                xv.w = fmaxf(fmaf(hv.w, inv, xv.w), 0.f);
            }
            *reinterpret_cast<float4*>(&Xs[row * 68 + k4]) = xv;
            *reinterpret_cast<float4*>(&Wsm[row * 68 + k4]) =
                *reinterpret_cast<const float4*>(&Ws_g[(size_t)row * 64 + k4]);
            *reinterpret_cast<float4*>(&Wnm[row * 68 + k4]) =
                *reinterpret_cast<const float4*>(&Wn_g[(size_t)row * 64 + k4]);
        }
        __syncthreads();
        const int kk0 = grp * 32;
#pragma unroll 4
        for (int kk = kk0; kk < kk0 + 32; ++kk) {
            float av[4], bs[4], bn[4];
#pragma unroll
            for (int j = 0; j < 4; ++j) av[j] = Xs[(ry * 4 + j) * 68 + kk];
#pragma unroll
            for (int i = 0; i < 4; ++i) {
                bs[i] = Wsm[kk * 68 + cx + 16 * i];
                bn[i] = Wnm[kk * 68 + cx + 16 * i];
            }
#pragma unroll
            for (int j = 0; j < 4; ++j)
#pragma unroll
                for (int i = 0; i < 4; ++i) {
                    acc_s[j][i] += av[j] * bs[i];
                    acc_n[j][i] += av[j] * bn[i];
                }
        }
        __syncthreads();   // all reads of Xs/Ws/Wn done -> safe to reuse
    }

    // combine: grp1 partials into reused smem base, stride 33
    if (grp == 1) {
        int o = t * 33;
#pragma unroll
        for (int j = 0; j < 4; ++j)
#pragma unroll
            for (int i = 0; i < 4; ++i) {
                smem[o + j * 4 + i]      = acc_s[j][i];
                smem[o + 16 + j * 4 + i] = acc_n[j][i];
            }
    }
    __syncthreads();
    if (grp == 0) {
        int o = t * 33;
#pragma unroll
        for (int j = 0; j < 4; ++j)
#pragma unroll
            for (int i = 0; i < 4; ++i) {
                acc_s[j][i] += smem[o + j * 4 + i];
                acc_n[j][i] += smem[o + 16 + j * 4 + i];
            }
#pragma unroll
        for (int j = 0; j < 4; ++j) {
            int r = row0 + ry * 4 + j;
            if (r < M) {
#pragma unroll
                for (int i = 0; i < 4; ++i) {
                    int col = cx + 16 * i;
                    S[(size_t)r * DH + col] = acc_s[j][i] + bias[col];
                    P[(size_t)r * DH + col] = f2bf(acc_n[j][i]);
                }
            }
        }
    }
}

// ---- aggregation: src-bucket LDS slice, wave-per-(dst,bucket) row ----------
// grid = NSB * DTILES blocks x 1024 threads. LDS = 1250*64 bf16 = 160,000 B.
// ATOMIC-FREE: each row has ONE writer -> plain coalesced 256B store into
// its per-bucket partial plane. Empty rows skipped (consumer guards on cnt).
__global__ __launch_bounds__(1024) void agg_kernel(
    const unsigned short* __restrict__ P, const int* __restrict__ cnt8,
    const unsigned short* __restrict__ es16, float* __restrict__ Hn_part,
    int M, int npb8) {
    __shared__ __align__(16) unsigned short sP[MAXNPB * DH];
    int tid = threadIdx.x;
    int sb    = blockIdx.x & (NSB - 1);
    int dtile = blockIdx.x >> 3;
    int s0 = sb * npb8;
    int snodes = min(npb8, M - s0);

    // stage this bucket's P slice (coalesced uint4)
    {
        const uint4* gp = reinterpret_cast<const uint4*>(P + (size_t)s0 * DH);
        int cnt = snodes * 8;   // 128 B/node / 16 B
        for (int j = tid; j < cnt; j += 1024)
            *reinterpret_cast<uint4*>(&sP[j * 8]) = gp[j];
    }
    __syncthreads();

    int lane = tid & 63, wid = tid >> 6;
    int dpb  = (M + DTILES - 1) / DTILES;
    int d0t  = dtile * dpb;
    int dend = min(d0t + dpb, M);

    for (int dstn = d0t + wid; dstn < dend; dstn += 16) {
        int key = dstn * NSB + sb;
        int cnt = min(cnt8[key], CAP);
        if (cnt == 0) continue;
        size_t base = (size_t)key * CAP;
        float acc = 0.f;
        int cmax = cnt - 1;
        for (int e = 0; e < cnt; e += 4) {
            int i0 = es16[base + min(e + 0, cmax)];
            int i1 = es16[base + min(e + 1, cmax)];
            int i2 = es16[base + min(e + 2, cmax)];
            int i3 = es16[base + min(e + 3, cmax)];
            float m1 = (e + 1 < cnt) ? 1.f : 0.f;
            float m2 = (e + 2 < cnt) ? 1.f : 0.f;
            float m3 = (e + 3 < cnt) ? 1.f : 0.f;
            float f0 = bfu(sP[(size_t)i0 * DH + lane]);
            float f1 = bfu(sP[(size_t)i1 * DH + lane]);
            float f2 = bfu(sP[(size_t)i2 * DH + lane]);
            float f3 = bfu(sP[(size_t)i3 * DH + lane]);
            acc += f0;                       // e+0 always valid in-loop
            acc = fmaf(m1, f1, acc);
            acc = fmaf(m2, f2, acc);
            acc = fmaf(m3, f3, acc);
        }
        Hn_part[(size_t)key * DH + lane] = acc;   // plain coalesced 256 B
    }
}

// ---- fused finish + readout (last-block-done ticket) ----------------------
// finish: H = S + sum(partials)/deg (no relu) + per-graph register
// accumulation, one coalesced flush per graph-change (graph_id sorted).
__global__ __launch_bounds__(256) void finish_readout_kernel(
    const float* __restrict__ S, const float* __restrict__ Hn_part,
    const int* __restrict__ cnt8, const int* __restrict__ graph_id,
    float* __restrict__ H, float* __restrict__ gsum, float* __restrict__ gcnt,
    const float* __restrict__ Wc, const float* __restrict__ bc,
    float* __restrict__ out, float* __restrict__ out_feat,
    unsigned int* __restrict__ done, int M, int fb) {
    int tid  = threadIdx.x;
    int lane = tid & 63;
    int wv   = tid >> 6;
    {   // ---- finish work ----
        int wid = blockIdx.x * 4 + wv;
        int nw  = fb * 4;
        int cpw = (M + nw - 1) / nw;
        int n0 = wid * cpw, n1 = min(n0 + cpw, M);
        if (n0 < n1) {
            float acc = 0.f;
            int cnt = 0;
            int cur = graph_id[n0];
            for (int n = n0; n < n1; ++n) {
                int gid = graph_id[n];
                if (gid != cur) {
                    atomicAdd(&gsum[cur * DH + lane], acc);
                    if (lane == 0) atomicAdd(&gcnt[cur], (float)cnt);
                    acc = 0.f; cnt = 0; cur = gid;
                }
                const int4* cp = reinterpret_cast<const int4*>(&cnt8[n * NSB]);
                int4 c0 = cp[0], c1 = cp[1];
                int ca[8] = {c0.x, c0.y, c0.z, c0.w, c1.x, c1.y, c1.z, c1.w};
                int deg = ca[0] + ca[1] + ca[2] + ca[3] +
                          ca[4] + ca[5] + ca[6] + ca[7];
                float hn = 0.f;
                size_t pb = (size_t)n * NSB * DH + lane;
#pragma unroll
                for (int b = 0; b < NSB; ++b)
                    if (ca[b] > 0) hn += Hn_part[pb + b * DH];
                float inv = 1.f / fmaxf((float)deg, 1.f);
                size_t o = (size_t)n * DH + lane;
                float val = fmaf(hn, inv, S[o]);
                H[o] = val;
                acc += val;
                ++cnt;
            }
            atomicAdd(&gsum[cur * DH + lane], acc);
            if (lane == 0) atomicAdd(&gcnt[cur], (float)cnt);
        }
    }

    // ---- last-block ticket ----
    __shared__ unsigned int s_ticket;
    __syncthreads();
    if (tid == 0) {
        __threadfence();   // release: publish this block's gsum/gcnt/H
        s_ticket = __hip_atomic_fetch_add(done, 1u, __ATOMIC_ACQ_REL,
                                          __HIP_MEMORY_SCOPE_AGENT);
    }
    __syncthreads();
    if (s_ticket != (unsigned int)(fb - 1)) return;
    if (tid == 0) __threadfence();   // acquire: see all blocks' gsum/gcnt
    __syncthreads();

    // ---- readout by the last block (256 threads, 4 entries each) ----
    __shared__ float ofs[NG][DH];
#pragma unroll
    for (int q = 0; q < 4; ++q) {
        int idx = tid + 256 * q;            // 0..1023 = (g,d)
        int g = idx >> 6, d = idx & 63;
        float of = gsum[idx] / fmaxf(gcnt[g], 1.0f);
        out_feat[idx] = of;
        ofs[g][d] = of;
    }
    __syncthreads();
    if (tid < NG * 2) {
        int gg = tid >> 1, cc = tid & 1;
        float accv = bc[cc];
#pragma unroll 8
        for (int dd = 0; dd < DH; ++dd) accv += ofs[gg][dd] * Wc[dd * 2 + cc];
        out[gg * 2 + cc] = accv;
    }
}

extern "C" void kernel_launch(void* const* d_in, const int* in_sizes, int n_in,
                              void* d_out, int out_size, void* d_ws, size_t ws_size,
                              hipStream_t stream) {
    const float* feat     = (const float*)d_in[0];
    const int*   src      = (const int*)d_in[1];
    const int*   dst      = (const int*)d_in[2];
    const int*   graph_id = (const int*)d_in[3];
    const float* Ws1 = (const float*)d_in[4];
    const float* Wn1 = (const float*)d_in[5];
    const float* b1  = (const float*)d_in[6];
    const float* Ws2 = (const float*)d_in[7];
    const float* Wn2 = (const float*)d_in[8];
    const float* b2  = (const float*)d_in[9];
    const float* Ws3 = (const float*)d_in[10];
    const float* Wn3 = (const float*)d_in[11];
    const float* b3  = (const float*)d_in[12];
    const float* Wc  = (const float*)d_in[13];
    const float* bc  = (const float*)d_in[14];

    const int M  = in_sizes[3];     // 10000 nodes
    const int E  = in_sizes[1];     // 320000 edges
    const int M2 = M * NSB;         // 80000 (dst,bucket) rows
    const int npb8 = (M + NSB - 1) / NSB;   // 1250 (<= MAXNPB)

    float* out      = (float*)d_out;             // 16 x 2
    float* out_feat = out + NG * 2;              // 16 x 64
    float* Hbuf     = out_feat + NG * DH;        // 10000 x 64 (final h)

    // workspace layout (256B-aligned carves)
    char* w = (char*)d_ws;
    size_t off = 0;
    auto carve = [&](size_t bytes) {
        size_t o = off;
        off = (off + bytes + 255) & ~(size_t)255;
        return o;
    };
    int*   cnt8  = (int*)  (w + carve((size_t)M2 * 4));
    float* gsum  = (float*)(w + carve((size_t)NG * DH * 4));
    float* gcnt  = (float*)(w + carve((size_t)NG * 4));
    unsigned int* done = (unsigned int*)(w + carve(4));
    size_t zero_bytes = off;                       // cnt8 + gsum + gcnt + done
    unsigned short* es16 = (unsigned short*)(w + carve((size_t)M2 * CAP * 2)); // 5.12 MB
    float* Sbuf  = (float*)(w + carve((size_t)M * DH * 4));
    unsigned short* Pbuf = (unsigned short*)(w + carve((size_t)M * DH * 2));
    float* Hn_part = (float*)(w + carve((size_t)M2 * DH * 4));   // 20.48 MB
    (void)ws_size; (void)n_in; (void)out_size;

    (void)hipMemsetAsync(d_ws, 0, zero_bytes, stream);

    int gb = (M + 63) / 64;          // 157 gemm blocks
    int eb = (E + 511) / 512;        // 625 build blocks (512 thr)
    int ab = NSB * DTILES;           // 256 agg blocks (1/CU)
    int fb = 160;                    // finish blocks: 640 waves

    // layer 1 (K=256, split-K) + CSR build, ONE dispatch
    gemm1_build_kernel<<<gb + eb, 512, 0, stream>>>(
        feat, Ws1, Wn1, b1, Sbuf, Pbuf,
        src, dst, cnt8, es16, M, E, npb8, gb);
    agg_kernel<<<ab, 1024, 0, stream>>>(Pbuf, cnt8, es16, Hn_part, M, npb8);

    // layer 2 (K=64, split-kk): X = relu(S1 + sum(partials)/deg) fused;
    // in-place S is block-safe (each block reads only its own rows first)
    gemm_dual_kernel<<<gb, 512, 0, stream>>>(
        Sbuf, Ws2, Wn2, b2, Hn_part, cnt8, Sbuf, Pbuf, M);
    agg_kernel<<<ab, 1024, 0, stream>>>(Pbuf, cnt8, es16, Hn_part, M, npb8);

    // layer 3 (K=64, split-kk): X = relu(S2 + sum(partials)/deg) fused
    gemm_dual_kernel<<<gb, 512, 0, stream>>>(
        Sbuf, Ws3, Wn3, b3, Hn_part, cnt8, Sbuf, Pbuf, M);
    agg_kernel<<<ab, 1024, 0, stream>>>(Pbuf, cnt8, es16, Hn_part, M, npb8);

    // finish layer 3 + readout (fused via last-block-done ticket)
    finish_readout_kernel<<<fb, 256, 0, stream>>>(
        Sbuf, Hn_part, cnt8, graph_id, Hbuf, gsum, gcnt,
        Wc, bc, out, out_feat, done, M, fb);
}

// Round 11
// 236.846 us; speedup vs baseline: 1.0937x; 1.0937x over previous
//
#include <hip/hip_runtime.h>

// ---------------------------------------------------------------------------
// SAGE 3-layer GNN.  (R18 = R17 + branchless MLP plane-sum + 4x finish waves)
//   Per layer: S = X@W_self + b (fp32) ; P = X@W_neigh (bf16 row-major)
//              h[i] = act( S[i] + (sum_{j in N_in(i)} P[j]) / max(deg_i,1) )
//
// Evidence log:
//   R0..R5: random row-gather agg ~150us = per-CU gather service wall.
//   R8 FAILED: dim-sliced LDS planes (32x edge visits).
//   R9 WIN: src-bucket LDS slicing. R10 WIN: sorted-graph_id finish.
//   R11 WIN: one-pass fixed-cap CSR build. 255.9us.
//   R12/R13/R14: persistent-kernel route FAILED. Reverted.
//   R15 WIN (249.1): build fused into gemm1; readout ticket-fused.
//   R16 WIN (232.5): split-K wave-group GEMMs (2 waves/SIMD).
//   R17 FAILED (259.0): atomic-free agg partial planes SAVED ~18us in
//     aggs/gemms BUT finish +44us (53.8us visible): guarded 8-plane sum =
//     serial branch-gated HBM-latency chain at 640 waves (occ 5.6%,
//     265GB/s). Consumer MLP, not the plane idea, was the bug.
//   R18 (this round): keep atomic-free aggs. (1) Branchless plane sum:
//     unconditional 8 independent loads + v_cndmask select (NaN-safe vs
//     stale poison; never multiply) in finish AND gemm2/3 loader.
//     (2) finish fb 160->320 blocks (1280 waves, 8 nodes/wave; ~1300
//     coalesced flushes, ~81/line ~ 3us serialization).
//   Predicted: finish 53.8 -> 12-18us (FETCH ~11->~22MB, parallel issue),
//     total 259 -> ~210-220. Fallback: finish>25us -> revert R16 consumers.
// ---------------------------------------------------------------------------

#define DH 64
#define NG 16
#define NSB 8        // src buckets
#define DTILES 32    // dst tiles -> grid 8*32 = 256 agg blocks (1/CU)
#define MAXNPB 1250  // max nodes per bucket (M <= 10000)
#define CAP 32       // edge slots per (dst,bucket) row; Poisson(4) tail ~1e-19
#define TILE_F 4352  // 64*68 floats per LDS tile

__device__ __forceinline__ unsigned short f2bf(float f) {
    unsigned int u = __float_as_uint(f);
    unsigned int r = (u + 0x7FFFu + ((u >> 16) & 1u)) >> 16;   // RNE
    return (unsigned short)r;
}
__device__ __forceinline__ float bfu(unsigned short v) {
    return __uint_as_float(((unsigned int)v) << 16);
}

// ---- fused: layer-1 dual GEMM (blocks [0,gb)) + CSR build ([gb,gb+eb)) ----
// gemm: split-K wave groups (R16-proven). build: one edge per thread,
// p=atomicAdd(cnt8[key]); es16[key*CAP+p] = LOCAL src idx (ushort).
__global__ __launch_bounds__(512) void gemm1_build_kernel(
    const float* __restrict__ X, const float* __restrict__ Ws_g,
    const float* __restrict__ Wn_g, const float* __restrict__ bias,
    float* __restrict__ S, unsigned short* __restrict__ P,
    const int* __restrict__ src, const int* __restrict__ dst,
    int* __restrict__ cnt8, unsigned short* __restrict__ es16,
    int M, int E, int npb8, int gb) {
    constexpr int K = 256;
    int tid = threadIdx.x;

    if ((int)blockIdx.x >= gb) {          // ---- build part ----
        int i = ((int)blockIdx.x - gb) * 512 + tid;
        if (i < E) {
            int s = src[i];
            int b = s / npb8;
            int k = dst[i] * NSB + b;
            int p = atomicAdd(&cnt8[k], 1);
            if (p < CAP)                   // clamp: memory-safe
                es16[(size_t)k * CAP + p] = (unsigned short)(s - b * npb8);
        }
        return;
    }

    // ---- gemm part: split-K over 2 wave groups (R16-proven) ----
    __shared__ float smem[6 * TILE_F];    // grp0: Xs,Ws,Wn ; grp1: Xs,Ws,Wn
    const int grp = tid >> 8;             // 0: waves 0-3, 1: waves 4-7
    const int t   = tid & 255;
    const int cx = t & 15;
    const int ry = t >> 4;
    float* Xs  = smem + grp * 3 * TILE_F;
    float* Wsm = Xs + TILE_F;
    float* Wnm = Wsm + TILE_F;
    const int row0 = blockIdx.x * 64;
    float acc_s[4][4] = {{0.f}};
    float acc_n[4][4] = {{0.f}};

    for (int st = 0; st < 2; ++st) {
        const int kc = grp * 128 + st * 64;
#pragma unroll
        for (int it = 0; it < 4; ++it) {
            int q = t + 256 * it;         // 0..1023
            int row = q >> 4;
            int k4 = (q & 15) * 4;
            float4 xv = make_float4(0.f, 0.f, 0.f, 0.f);
            int gr = row0 + row;
            if (gr < M)
                xv = *reinterpret_cast<const float4*>(&X[(size_t)gr * K + kc + k4]);
            *reinterpret_cast<float4*>(&Xs[row * 68 + k4]) = xv;
            *reinterpret_cast<float4*>(&Wsm[row * 68 + k4]) =
                *reinterpret_cast<const float4*>(&Ws_g[(size_t)(kc + row) * 64 + k4]);
            *reinterpret_cast<float4*>(&Wnm[row * 68 + k4]) =
                *reinterpret_cast<const float4*>(&Wn_g[(size_t)(kc + row) * 64 + k4]);
        }
        __syncthreads();
#pragma unroll 4
        for (int kk = 0; kk < 64; ++kk) {
            float av[4], bs[4], bn[4];
#pragma unroll
            for (int j = 0; j < 4; ++j) av[j] = Xs[(ry * 4 + j) * 68 + kk];
#pragma unroll
            for (int i = 0; i < 4; ++i) {
                bs[i] = Wsm[kk * 68 + cx + 16 * i];
                bn[i] = Wnm[kk * 68 + cx + 16 * i];
            }
#pragma unroll
            for (int j = 0; j < 4; ++j)
#pragma unroll
                for (int i = 0; i < 4; ++i) {
                    acc_s[j][i] += av[j] * bs[i];
                    acc_n[j][i] += av[j] * bn[i];
                }
        }
        __syncthreads();
    }

    // combine: grp1 -> its own (dead) LDS region, stride 33 (bank-free)
    float* flat = smem + 3 * TILE_F;
    if (grp == 1) {
        int o = t * 33;
#pragma unroll
        for (int j = 0; j < 4; ++j)
#pragma unroll
            for (int i = 0; i < 4; ++i) {
                flat[o + j * 4 + i]      = acc_s[j][i];
                flat[o + 16 + j * 4 + i] = acc_n[j][i];
            }
    }
    __syncthreads();
    if (grp == 0) {
        int o = t * 33;
#pragma unroll
        for (int j = 0; j < 4; ++j)
#pragma unroll
            for (int i = 0; i < 4; ++i) {
                acc_s[j][i] += flat[o + j * 4 + i];
                acc_n[j][i] += flat[o + 16 + j * 4 + i];
            }
#pragma unroll
        for (int j = 0; j < 4; ++j) {
            int r = row0 + ry * 4 + j;
            if (r < M) {
#pragma unroll
                for (int i = 0; i < 4; ++i) {
                    int col = cx + 16 * i;
                    S[(size_t)r * DH + col] = acc_s[j][i] + bias[col];
                    P[(size_t)r * DH + col] = f2bf(acc_n[j][i]);
                }
            }
        }
    }
}

// ---- dual GEMM layers 2/3 (K=64): X = relu(S + sum(partials)/deg) ---------
// 512 threads, split-kk wave groups (R16). Loader: BRANCHLESS plane sum —
// 8 unconditional independent loads (parallel issue), cndmask select
// (NaN-safe vs stale poison planes).
__global__ __launch_bounds__(512) void gemm_dual_kernel(
    const float* __restrict__ X, const float* __restrict__ Ws_g,
    const float* __restrict__ Wn_g, const float* __restrict__ bias,
    const float* __restrict__ Hn_part, const int* __restrict__ cnt8,
    float* __restrict__ S, unsigned short* __restrict__ P, int M) {
    constexpr int K = 64;
    __shared__ float smem[3 * TILE_F];    // Xs, Ws, Wn (combine reuses base)
    int tid = threadIdx.x;
    const int grp = tid >> 8;
    const int t   = tid & 255;
    const int cx = t & 15;
    const int ry = t >> 4;
    float* Xs  = smem;
    float* Wsm = smem + TILE_F;
    float* Wnm = smem + 2 * TILE_F;
    const int row0 = blockIdx.x * 64;
    float acc_s[4][4] = {{0.f}};
    float acc_n[4][4] = {{0.f}};

    {   // stage by all 512 threads (2 passes cover 64 rows x 16 k4-groups)
#pragma unroll
        for (int it = 0; it < 2; ++it) {
            int q = tid + 512 * it;       // 0..1023
            int row = q >> 4;
            int k4 = (q & 15) * 4;
            float4 xv = make_float4(0.f, 0.f, 0.f, 0.f);
            int gr = row0 + row;
            if (gr < M) {
                xv = *reinterpret_cast<const float4*>(&X[(size_t)gr * K + k4]);
                const int4* cp = reinterpret_cast<const int4*>(&cnt8[gr * NSB]);
                int4 c0 = cp[0], c1 = cp[1];
                int ca[8] = {c0.x, c0.y, c0.z, c0.w, c1.x, c1.y, c1.z, c1.w};
                int deg = ca[0] + ca[1] + ca[2] + ca[3] +
                          ca[4] + ca[5] + ca[6] + ca[7];
                // branchless: 8 unconditional loads, then select
                float4 pv[8];
                size_t pb = (size_t)gr * NSB * DH + k4;
#pragma unroll
                for (int b = 0; b < NSB; ++b)
                    pv[b] = *reinterpret_cast<const float4*>(&Hn_part[pb + b * DH]);
                float4 hv = make_float4(0.f, 0.f, 0.f, 0.f);
#pragma unroll
                for (int b = 0; b < NSB; ++b) {
                    bool use = ca[b] > 0;
                    hv.x += use ? pv[b].x : 0.f;
                    hv.y += use ? pv[b].y : 0.f;
                    hv.z += use ? pv[b].z : 0.f;
                    hv.w += use ? pv[b].w : 0.f;
                }
                float inv = 1.f / fmaxf((float)deg, 1.f);
                xv.x = fmaxf(fmaf(hv.x, inv, xv.x), 0.f);
                xv.y = fmaxf(fmaf(hv.y, inv, xv.y), 0.f);
                xv.z = fmaxf(fmaf(hv.z, inv, xv.z), 0.f);
                xv.w = fmaxf(fmaf(hv.w, inv, xv.w), 0.f);
            }
            *reinterpret_cast<float4*>(&Xs[row * 68 + k4]) = xv;
            *reinterpret_cast<float4*>(&Wsm[row * 68 + k4]) =
                *reinterpret_cast<const float4*>(&Ws_g[(size_t)row * 64 + k4]);
            *reinterpret_cast<float4*>(&Wnm[row * 68 + k4]) =
                *reinterpret_cast<const float4*>(&Wn_g[(size_t)row * 64 + k4]);
        }
        __syncthreads();
        const int kk0 = grp * 32;
#pragma unroll 4
        for (int kk = kk0; kk < kk0 + 32; ++kk) {
            float av[4], bs[4], bn[4];
#pragma unroll
            for (int j = 0; j < 4; ++j) av[j] = Xs[(ry * 4 + j) * 68 + kk];
#pragma unroll
            for (int i = 0; i < 4; ++i) {
                bs[i] = Wsm[kk * 68 + cx + 16 * i];
                bn[i] = Wnm[kk * 68 + cx + 16 * i];
            }
#pragma unroll
            for (int j = 0; j < 4; ++j)
#pragma unroll
                for (int i = 0; i < 4; ++i) {
                    acc_s[j][i] += av[j] * bs[i];
                    acc_n[j][i] += av[j] * bn[i];
                }
        }
        __syncthreads();   // all reads of Xs/Ws/Wn done -> safe to reuse
    }

    // combine: grp1 partials into reused smem base, stride 33
    if (grp == 1) {
        int o = t * 33;
#pragma unroll
        for (int j = 0; j < 4; ++j)
#pragma unroll
            for (int i = 0; i < 4; ++i) {
                smem[o + j * 4 + i]      = acc_s[j][i];
                smem[o + 16 + j * 4 + i] = acc_n[j][i];
            }
    }
    __syncthreads();
    if (grp == 0) {
        int o = t * 33;
#pragma unroll
        for (int j = 0; j < 4; ++j)
#pragma unroll
            for (int i = 0; i < 4; ++i) {
                acc_s[j][i] += smem[o + j * 4 + i];
                acc_n[j][i] += smem[o + 16 + j * 4 + i];
            }
#pragma unroll
        for (int j = 0; j < 4; ++j) {
            int r = row0 + ry * 4 + j;
            if (r < M) {
#pragma unroll
                for (int i = 0; i < 4; ++i) {
                    int col = cx + 16 * i;
                    S[(size_t)r * DH + col] = acc_s[j][i] + bias[col];
                    P[(size_t)r * DH + col] = f2bf(acc_n[j][i]);
                }
            }
        }
    }
}

// ---- aggregation: src-bucket LDS slice, wave-per-(dst,bucket) row ----------
// grid = NSB * DTILES blocks x 1024 threads. LDS = 1250*64 bf16 = 160,000 B.
// ATOMIC-FREE: each row has ONE writer -> plain coalesced 256B store into
// its per-bucket partial plane. Empty rows skipped (consumer guards on cnt).
__global__ __launch_bounds__(1024) void agg_kernel(
    const unsigned short* __restrict__ P, const int* __restrict__ cnt8,
    const unsigned short* __restrict__ es16, float* __restrict__ Hn_part,
    int M, int npb8) {
    __shared__ __align__(16) unsigned short sP[MAXNPB * DH];
    int tid = threadIdx.x;
    int sb    = blockIdx.x & (NSB - 1);
    int dtile = blockIdx.x >> 3;
    int s0 = sb * npb8;
    int snodes = min(npb8, M - s0);

    // stage this bucket's P slice (coalesced uint4)
    {
        const uint4* gp = reinterpret_cast<const uint4*>(P + (size_t)s0 * DH);
        int cnt = snodes * 8;   // 128 B/node / 16 B
        for (int j = tid; j < cnt; j += 1024)
            *reinterpret_cast<uint4*>(&sP[j * 8]) = gp[j];
    }
    __syncthreads();

    int lane = tid & 63, wid = tid >> 6;
    int dpb  = (M + DTILES - 1) / DTILES;
    int d0t  = dtile * dpb;
    int dend = min(d0t + dpb, M);

    for (int dstn = d0t + wid; dstn < dend; dstn += 16) {
        int key = dstn * NSB + sb;
        int cnt = min(cnt8[key], CAP);
        if (cnt == 0) continue;
        size_t base = (size_t)key * CAP;
        float acc = 0.f;
        int cmax = cnt - 1;
        for (int e = 0; e < cnt; e += 4) {
            int i0 = es16[base + min(e + 0, cmax)];
            int i1 = es16[base + min(e + 1, cmax)];
            int i2 = es16[base + min(e + 2, cmax)];
            int i3 = es16[base + min(e + 3, cmax)];
            float m1 = (e + 1 < cnt) ? 1.f : 0.f;
            float m2 = (e + 2 < cnt) ? 1.f : 0.f;
            float m3 = (e + 3 < cnt) ? 1.f : 0.f;
            float f0 = bfu(sP[(size_t)i0 * DH + lane]);
            float f1 = bfu(sP[(size_t)i1 * DH + lane]);
            float f2 = bfu(sP[(size_t)i2 * DH + lane]);
            float f3 = bfu(sP[(size_t)i3 * DH + lane]);
            acc += f0;                       // e+0 always valid in-loop
            acc = fmaf(m1, f1, acc);
            acc = fmaf(m2, f2, acc);
            acc = fmaf(m3, f3, acc);
        }
        Hn_part[(size_t)key * DH + lane] = acc;   // plain coalesced 256 B
    }
}

// ---- fused finish + readout (last-block-done ticket) ----------------------
// finish: H = S + sum(partials)/deg (no relu) + per-graph register
// accumulation, one coalesced flush per graph-change (graph_id sorted).
// BRANCHLESS plane sum: 8 unconditional loads issue in parallel; cndmask
// select drops stale planes (NaN-safe). fb=320 -> 1280 waves for TLP.
__global__ __launch_bounds__(256) void finish_readout_kernel(
    const float* __restrict__ S, const float* __restrict__ Hn_part,
    const int* __restrict__ cnt8, const int* __restrict__ graph_id,
    float* __restrict__ H, float* __restrict__ gsum, float* __restrict__ gcnt,
    const float* __restrict__ Wc, const float* __restrict__ bc,
    float* __restrict__ out, float* __restrict__ out_feat,
    unsigned int* __restrict__ done, int M, int fb) {
    int tid  = threadIdx.x;
    int lane = tid & 63;
    int wv   = tid >> 6;
    {   // ---- finish work ----
        int wid = blockIdx.x * 4 + wv;
        int nw  = fb * 4;
        int cpw = (M + nw - 1) / nw;
        int n0 = wid * cpw, n1 = min(n0 + cpw, M);
        if (n0 < n1) {
            float acc = 0.f;
            int cnt = 0;
            int cur = graph_id[n0];
            for (int n = n0; n < n1; ++n) {
                int gid = graph_id[n];
                if (gid != cur) {
                    atomicAdd(&gsum[cur * DH + lane], acc);
                    if (lane == 0) atomicAdd(&gcnt[cur], (float)cnt);
                    acc = 0.f; cnt = 0; cur = gid;
                }
                const int4* cp = reinterpret_cast<const int4*>(&cnt8[n * NSB]);
                int4 c0 = cp[0], c1 = cp[1];
                int ca[8] = {c0.x, c0.y, c0.z, c0.w, c1.x, c1.y, c1.z, c1.w};
                int deg = ca[0] + ca[1] + ca[2] + ca[3] +
                          ca[4] + ca[5] + ca[6] + ca[7];
                // branchless: 8 unconditional parallel loads, then select
                float pv[8];
                size_t pb = (size_t)n * NSB * DH + lane;
#pragma unroll
                for (int b = 0; b < NSB; ++b) pv[b] = Hn_part[pb + b * DH];
                float hn = 0.f;
#pragma unroll
                for (int b = 0; b < NSB; ++b) hn += (ca[b] > 0) ? pv[b] : 0.f;
                float inv = 1.f / fmaxf((float)deg, 1.f);
                size_t o = (size_t)n * DH + lane;
                float val = fmaf(hn, inv, S[o]);
                H[o] = val;
                acc += val;
                ++cnt;
            }
            atomicAdd(&gsum[cur * DH + lane], acc);
            if (lane == 0) atomicAdd(&gcnt[cur], (float)cnt);
        }
    }

    // ---- last-block ticket ----
    __shared__ unsigned int s_ticket;
    __syncthreads();
    if (tid == 0) {
        __threadfence();   // release: publish this block's gsum/gcnt/H
        s_ticket = __hip_atomic_fetch_add(done, 1u, __ATOMIC_ACQ_REL,
                                          __HIP_MEMORY_SCOPE_AGENT);
    }
    __syncthreads();
    if (s_ticket != (unsigned int)(fb - 1)) return;
    if (tid == 0) __threadfence();   // acquire: see all blocks' gsum/gcnt
    __syncthreads();

    // ---- readout by the last block (256 threads, 4 entries each) ----
    __shared__ float ofs[NG][DH];
#pragma unroll
    for (int q = 0; q < 4; ++q) {
        int idx = tid + 256 * q;            // 0..1023 = (g,d)
        int g = idx >> 6, d = idx & 63;
        float of = gsum[idx] / fmaxf(gcnt[g], 1.0f);
        out_feat[idx] = of;
        ofs[g][d] = of;
    }
    __syncthreads();
    if (tid < NG * 2) {
        int gg = tid >> 1, cc = tid & 1;
        float accv = bc[cc];
#pragma unroll 8
        for (int dd = 0; dd < DH; ++dd) accv += ofs[gg][dd] * Wc[dd * 2 + cc];
        out[gg * 2 + cc] = accv;
    }
}

extern "C" void kernel_launch(void* const* d_in, const int* in_sizes, int n_in,
                              void* d_out, int out_size, void* d_ws, size_t ws_size,
                              hipStream_t stream) {
    const float* feat     = (const float*)d_in[0];
    const int*   src      = (const int*)d_in[1];
    const int*   dst      = (const int*)d_in[2];
    const int*   graph_id = (const int*)d_in[3];
    const float* Ws1 = (const float*)d_in[4];
    const float* Wn1 = (const float*)d_in[5];
    const float* b1  = (const float*)d_in[6];
    const float* Ws2 = (const float*)d_in[7];
    const float* Wn2 = (const float*)d_in[8];
    const float* b2  = (const float*)d_in[9];
    const float* Ws3 = (const float*)d_in[10];
    const float* Wn3 = (const float*)d_in[11];
    const float* b3  = (const float*)d_in[12];
    const float* Wc  = (const float*)d_in[13];
    const float* bc  = (const float*)d_in[14];

    const int M  = in_sizes[3];     // 10000 nodes
    const int E  = in_sizes[1];     // 320000 edges
    const int M2 = M * NSB;         // 80000 (dst,bucket) rows
    const int npb8 = (M + NSB - 1) / NSB;   // 1250 (<= MAXNPB)

    float* out      = (float*)d_out;             // 16 x 2
    float* out_feat = out + NG * 2;              // 16 x 64
    float* Hbuf     = out_feat + NG * DH;        // 10000 x 64 (final h)

    // workspace layout (256B-aligned carves)
    char* w = (char*)d_ws;
    size_t off = 0;
    auto carve = [&](size_t bytes) {
        size_t o = off;
        off = (off + bytes + 255) & ~(size_t)255;
        return o;
    };
    int*   cnt8  = (int*)  (w + carve((size_t)M2 * 4));
    float* gsum  = (float*)(w + carve((size_t)NG * DH * 4));
    float* gcnt  = (float*)(w + carve((size_t)NG * 4));
    unsigned int* done = (unsigned int*)(w + carve(4));
    size_t zero_bytes = off;                       // cnt8 + gsum + gcnt + done
    unsigned short* es16 = (unsigned short*)(w + carve((size_t)M2 * CAP * 2)); // 5.12 MB
    float* Sbuf  = (float*)(w + carve((size_t)M * DH * 4));
    unsigned short* Pbuf = (unsigned short*)(w + carve((size_t)M * DH * 2));
    float* Hn_part = (float*)(w + carve((size_t)M2 * DH * 4));   // 20.48 MB
    (void)ws_size; (void)n_in; (void)out_size;

    (void)hipMemsetAsync(d_ws, 0, zero_bytes, stream);

    int gb = (M + 63) / 64;          // 157 gemm blocks
    int eb = (E + 511) / 512;        // 625 build blocks (512 thr)
    int ab = NSB * DTILES;           // 256 agg blocks (1/CU)
    int fb = 320;                    // finish blocks: 1280 waves (R18)

    // layer 1 (K=256, split-K) + CSR build, ONE dispatch
    gemm1_build_kernel<<<gb + eb, 512, 0, stream>>>(
        feat, Ws1, Wn1, b1, Sbuf, Pbuf,
        src, dst, cnt8, es16, M, E, npb8, gb);
    agg_kernel<<<ab, 1024, 0, stream>>>(Pbuf, cnt8, es16, Hn_part, M, npb8);

    // layer 2 (K=64, split-kk): X = relu(S1 + sum(partials)/deg) fused;
    // in-place S is block-safe (each block reads only its own rows first)
    gemm_dual_kernel<<<gb, 512, 0, stream>>>(
        Sbuf, Ws2, Wn2, b2, Hn_part, cnt8, Sbuf, Pbuf, M);
    agg_kernel<<<ab, 1024, 0, stream>>>(Pbuf, cnt8, es16, Hn_part, M, npb8);

    // layer 3 (K=64, split-kk): X = relu(S2 + sum(partials)/deg) fused
    gemm_dual_kernel<<<gb, 512, 0, stream>>>(
        Sbuf, Ws3, Wn3, b3, Hn_part, cnt8, Sbuf, Pbuf, M);
    agg_kernel<<<ab, 1024, 0, stream>>>(Pbuf, cnt8, es16, Hn_part, M, npb8);

    // finish layer 3 + readout (fused via last-block-done ticket)
    finish_readout_kernel<<<fb, 256, 0, stream>>>(
        Sbuf, Hn_part, cnt8, graph_id, Hbuf, gsum, gcnt,
        Wc, bc, out, out_feat, done, M, fb);
}

// Round 12
// 234.891 us; speedup vs baseline: 1.1028x; 1.0083x over previous
//
#include <hip/hip_runtime.h>

// ---------------------------------------------------------------------------
// SAGE 3-layer GNN.  (R19 = R18 + vectorized-LDS GEMM inner loop (b128 B-reads,
//                     float4/ushort4 epilogue via column remap))
//   Per layer: S = X@W_self + b (fp32) ; P = X@W_neigh (bf16 row-major)
//              h[i] = act( S[i] + (sum_{j in N_in(i)} P[j]) / max(deg_i,1) )
//
// Evidence log:
//   R0..R5: random row-gather agg ~150us = per-CU gather service wall.
//   R8 FAILED: dim-sliced LDS planes (32x edge visits).
//   R9 WIN: src-bucket LDS slicing. R10 WIN: sorted-graph_id finish.
//   R11 WIN: one-pass fixed-cap CSR build. 255.9us.
//   R12/R13/R14: persistent-kernel route FAILED. Reverted.
//   R15 WIN (249.1): build fused into gemm1; readout ticket-fused.
//   R16 WIN (232.5): split-K wave-group GEMMs (2 waves/SIMD).
//   R17 FAILED (259.0): atomic-free agg planes, but guarded consumer sum =
//     serial HBM-latency chain in finish (53.8us).
//   R18 PARTIAL (236.8): branchless plane-sum + 4x finish waves fixed finish
//     (<43us) but total ~flat vs R16 -> atomic-free arc net ~0. 30ms
//     gemm_dual row in profile = rocprof replay artifact (ignore).
//   R19 (this round): GEMM inner loop is LDS-issue-bound: 12 scalar
//     ds_read_b32 per kk (768/kc-step/thread) >> FMA cost. Column remap
//     (thread owns cols 4cx..4cx+3) makes both B-reads ds_read_b128
//     (16B-aligned, 2-way bank wrap = free) -> 6 instrs/kk; epilogue
//     becomes float4 S-store + ushort4 P-store. Bit-identical arithmetic.
//     Applied to gemm1_build + gemm_dual. Rest byte-identical R18.
//   Predicted: gemm1_build 30 -> 22-26, gemm2/3 12 -> 9-11,
//     total 236.8 -> ~218-228. If flat -> stage-barrier latency next.
// ---------------------------------------------------------------------------

#define DH 64
#define NG 16
#define NSB 8        // src buckets
#define DTILES 32    // dst tiles -> grid 8*32 = 256 agg blocks (1/CU)
#define MAXNPB 1250  // max nodes per bucket (M <= 10000)
#define CAP 32       // edge slots per (dst,bucket) row; Poisson(4) tail ~1e-19
#define TILE_F 4352  // 64*68 floats per LDS tile

__device__ __forceinline__ unsigned short f2bf(float f) {
    unsigned int u = __float_as_uint(f);
    unsigned int r = (u + 0x7FFFu + ((u >> 16) & 1u)) >> 16;   // RNE
    return (unsigned short)r;
}
__device__ __forceinline__ float bfu(unsigned short v) {
    return __uint_as_float(((unsigned int)v) << 16);
}

// ---- fused: layer-1 dual GEMM (blocks [0,gb)) + CSR build ([gb,gb+eb)) ----
// gemm: split-K wave groups (R16) + vectorized LDS reads (R19).
// build: one edge per thread, p=atomicAdd(cnt8[key]); es16 = LOCAL ushort idx.
__global__ __launch_bounds__(512) void gemm1_build_kernel(
    const float* __restrict__ X, const float* __restrict__ Ws_g,
    const float* __restrict__ Wn_g, const float* __restrict__ bias,
    float* __restrict__ S, unsigned short* __restrict__ P,
    const int* __restrict__ src, const int* __restrict__ dst,
    int* __restrict__ cnt8, unsigned short* __restrict__ es16,
    int M, int E, int npb8, int gb) {
    constexpr int K = 256;
    int tid = threadIdx.x;

    if ((int)blockIdx.x >= gb) {          // ---- build part ----
        int i = ((int)blockIdx.x - gb) * 512 + tid;
        if (i < E) {
            int s = src[i];
            int b = s / npb8;
            int k = dst[i] * NSB + b;
            int p = atomicAdd(&cnt8[k], 1);
            if (p < CAP)                   // clamp: memory-safe
                es16[(size_t)k * CAP + p] = (unsigned short)(s - b * npb8);
        }
        return;
    }

    // ---- gemm part: split-K over 2 wave groups; cols 4cx..4cx+3/thread ----
    __shared__ float smem[6 * TILE_F];    // grp0: Xs,Ws,Wn ; grp1: Xs,Ws,Wn
    const int grp = tid >> 8;             // 0: waves 0-3, 1: waves 4-7
    const int t   = tid & 255;
    const int cx = t & 15;                // col base = 4*cx
    const int ry = t >> 4;                // rows 4*ry..4*ry+3
    float* Xs  = smem + grp * 3 * TILE_F;
    float* Wsm = Xs + TILE_F;
    float* Wnm = Wsm + TILE_F;
    const int row0 = blockIdx.x * 64;
    float4 acc_s[4] = {{0.f,0.f,0.f,0.f},{0.f,0.f,0.f,0.f},
                       {0.f,0.f,0.f,0.f},{0.f,0.f,0.f,0.f}};
    float4 acc_n[4] = {{0.f,0.f,0.f,0.f},{0.f,0.f,0.f,0.f},
                       {0.f,0.f,0.f,0.f},{0.f,0.f,0.f,0.f}};

    for (int st = 0; st < 2; ++st) {
        const int kc = grp * 128 + st * 64;
#pragma unroll
        for (int it = 0; it < 4; ++it) {
            int q = t + 256 * it;         // 0..1023
            int row = q >> 4;
            int k4 = (q & 15) * 4;
            float4 xv = make_float4(0.f, 0.f, 0.f, 0.f);
            int gr = row0 + row;
            if (gr < M)
                xv = *reinterpret_cast<const float4*>(&X[(size_t)gr * K + kc + k4]);
            *reinterpret_cast<float4*>(&Xs[row * 68 + k4]) = xv;
            *reinterpret_cast<float4*>(&Wsm[row * 68 + k4]) =
                *reinterpret_cast<const float4*>(&Ws_g[(size_t)(kc + row) * 64 + k4]);
            *reinterpret_cast<float4*>(&Wnm[row * 68 + k4]) =
                *reinterpret_cast<const float4*>(&Wn_g[(size_t)(kc + row) * 64 + k4]);
        }
        __syncthreads();
#pragma unroll 4
        for (int kk = 0; kk < 64; ++kk) {
            float av[4];
#pragma unroll
            for (int j = 0; j < 4; ++j) av[j] = Xs[(ry * 4 + j) * 68 + kk];
            float4 bs4 = *reinterpret_cast<const float4*>(&Wsm[kk * 68 + cx * 4]);
            float4 bn4 = *reinterpret_cast<const float4*>(&Wnm[kk * 68 + cx * 4]);
#pragma unroll
            for (int j = 0; j < 4; ++j) {
                acc_s[j].x += av[j] * bs4.x; acc_s[j].y += av[j] * bs4.y;
                acc_s[j].z += av[j] * bs4.z; acc_s[j].w += av[j] * bs4.w;
                acc_n[j].x += av[j] * bn4.x; acc_n[j].y += av[j] * bn4.y;
                acc_n[j].z += av[j] * bn4.z; acc_n[j].w += av[j] * bn4.w;
            }
        }
        __syncthreads();
    }

    // combine: grp1 -> its own (dead) LDS region, stride 33 (bank-free)
    float* flat = smem + 3 * TILE_F;
    if (grp == 1) {
        int o = t * 33;
#pragma unroll
        for (int j = 0; j < 4; ++j) {
            flat[o + j * 4 + 0] = acc_s[j].x; flat[o + j * 4 + 1] = acc_s[j].y;
            flat[o + j * 4 + 2] = acc_s[j].z; flat[o + j * 4 + 3] = acc_s[j].w;
            flat[o + 16 + j * 4 + 0] = acc_n[j].x; flat[o + 16 + j * 4 + 1] = acc_n[j].y;
            flat[o + 16 + j * 4 + 2] = acc_n[j].z; flat[o + 16 + j * 4 + 3] = acc_n[j].w;
        }
    }
    __syncthreads();
    if (grp == 0) {
        int o = t * 33;
        int col = cx * 4;
        float4 b4 = *reinterpret_cast<const float4*>(&bias[col]);
#pragma unroll
        for (int j = 0; j < 4; ++j) {
            acc_s[j].x += flat[o + j * 4 + 0]; acc_s[j].y += flat[o + j * 4 + 1];
            acc_s[j].z += flat[o + j * 4 + 2]; acc_s[j].w += flat[o + j * 4 + 3];
            acc_n[j].x += flat[o + 16 + j * 4 + 0]; acc_n[j].y += flat[o + 16 + j * 4 + 1];
            acc_n[j].z += flat[o + 16 + j * 4 + 2]; acc_n[j].w += flat[o + 16 + j * 4 + 3];
            int r = row0 + ry * 4 + j;
            if (r < M) {
                float4 sv;
                sv.x = acc_s[j].x + b4.x; sv.y = acc_s[j].y + b4.y;
                sv.z = acc_s[j].z + b4.z; sv.w = acc_s[j].w + b4.w;
                *reinterpret_cast<float4*>(&S[(size_t)r * DH + col]) = sv;
                ushort4 pk;
                pk.x = f2bf(acc_n[j].x); pk.y = f2bf(acc_n[j].y);
                pk.z = f2bf(acc_n[j].z); pk.w = f2bf(acc_n[j].w);
                *reinterpret_cast<ushort4*>(&P[(size_t)r * DH + col]) = pk;
            }
        }
    }
}

// ---- dual GEMM layers 2/3 (K=64): X = relu(S + sum(partials)/deg) ---------
// 512 threads, split-kk wave groups (R16) + vectorized LDS reads (R19).
// Loader: branchless 8-plane sum (R18).
__global__ __launch_bounds__(512) void gemm_dual_kernel(
    const float* __restrict__ X, const float* __restrict__ Ws_g,
    const float* __restrict__ Wn_g, const float* __restrict__ bias,
    const float* __restrict__ Hn_part, const int* __restrict__ cnt8,
    float* __restrict__ S, unsigned short* __restrict__ P, int M) {
    constexpr int K = 64;
    __shared__ float smem[3 * TILE_F];    // Xs, Ws, Wn (combine reuses base)
    int tid = threadIdx.x;
    const int grp = tid >> 8;
    const int t   = tid & 255;
    const int cx = t & 15;                // col base = 4*cx
    const int ry = t >> 4;
    float* Xs  = smem;
    float* Wsm = smem + TILE_F;
    float* Wnm = smem + 2 * TILE_F;
    const int row0 = blockIdx.x * 64;
    float4 acc_s[4] = {{0.f,0.f,0.f,0.f},{0.f,0.f,0.f,0.f},
                       {0.f,0.f,0.f,0.f},{0.f,0.f,0.f,0.f}};
    float4 acc_n[4] = {{0.f,0.f,0.f,0.f},{0.f,0.f,0.f,0.f},
                       {0.f,0.f,0.f,0.f},{0.f,0.f,0.f,0.f}};

    {   // stage by all 512 threads (2 passes cover 64 rows x 16 k4-groups)
#pragma unroll
        for (int it = 0; it < 2; ++it) {
            int q = tid + 512 * it;       // 0..1023
            int row = q >> 4;
            int k4 = (q & 15) * 4;
            float4 xv = make_float4(0.f, 0.f, 0.f, 0.f);
            int gr = row0 + row;
            if (gr < M) {
                xv = *reinterpret_cast<const float4*>(&X[(size_t)gr * K + k4]);
                const int4* cp = reinterpret_cast<const int4*>(&cnt8[gr * NSB]);
                int4 c0 = cp[0], c1 = cp[1];
                int ca[8] = {c0.x, c0.y, c0.z, c0.w, c1.x, c1.y, c1.z, c1.w};
                int deg = ca[0] + ca[1] + ca[2] + ca[3] +
                          ca[4] + ca[5] + ca[6] + ca[7];
                // branchless: 8 unconditional loads, then select
                float4 pv[8];
                size_t pb = (size_t)gr * NSB * DH + k4;
#pragma unroll
                for (int b = 0; b < NSB; ++b)
                    pv[b] = *reinterpret_cast<const float4*>(&Hn_part[pb + b * DH]);
                float4 hv = make_float4(0.f, 0.f, 0.f, 0.f);
#pragma unroll
                for (int b = 0; b < NSB; ++b) {
                    bool use = ca[b] > 0;
                    hv.x += use ? pv[b].x : 0.f;
                    hv.y += use ? pv[b].y : 0.f;
                    hv.z += use ? pv[b].z : 0.f;
                    hv.w += use ? pv[b].w : 0.f;
                }
                float inv = 1.f / fmaxf((float)deg, 1.f);
                xv.x = fmaxf(fmaf(hv.x, inv, xv.x), 0.f);
                xv.y = fmaxf(fmaf(hv.y, inv, xv.y), 0.f);
                xv.z = fmaxf(fmaf(hv.z, inv, xv.z), 0.f);
                xv.w = fmaxf(fmaf(hv.w, inv, xv.w), 0.f);
            }
            *reinterpret_cast<float4*>(&Xs[row * 68 + k4]) = xv;
            *reinterpret_cast<float4*>(&Wsm[row * 68 + k4]) =
                *reinterpret_cast<const float4*>(&Ws_g[(size_t)row * 64 + k4]);
            *reinterpret_cast<float4*>(&Wnm[row * 68 + k4]) =
                *reinterpret_cast<const float4*>(&Wn_g[(size_t)row * 64 + k4]);
        }
        __syncthreads();
        const int kk0 = grp * 32;
#pragma unroll 4
        for (int kk = kk0; kk < kk0 + 32; ++kk) {
            float av[4];
#pragma unroll
            for (int j = 0; j < 4; ++j) av[j] = Xs[(ry * 4 + j) * 68 + kk];
            float4 bs4 = *reinterpret_cast<const float4*>(&Wsm[kk * 68 + cx * 4]);
            float4 bn4 = *reinterpret_cast<const float4*>(&Wnm[kk * 68 + cx * 4]);
#pragma unroll
            for (int j = 0; j < 4; ++j) {
                acc_s[j].x += av[j] * bs4.x; acc_s[j].y += av[j] * bs4.y;
                acc_s[j].z += av[j] * bs4.z; acc_s[j].w += av[j] * bs4.w;
                acc_n[j].x += av[j] * bn4.x; acc_n[j].y += av[j] * bn4.y;
                acc_n[j].z += av[j] * bn4.z; acc_n[j].w += av[j] * bn4.w;
            }
        }
        __syncthreads();   // all reads of Xs/Ws/Wn done -> safe to reuse
    }

    // combine: grp1 partials into reused smem base, stride 33
    if (grp == 1) {
        int o = t * 33;
#pragma unroll
        for (int j = 0; j < 4; ++j) {
            smem[o + j * 4 + 0] = acc_s[j].x; smem[o + j * 4 + 1] = acc_s[j].y;
            smem[o + j * 4 + 2] = acc_s[j].z; smem[o + j * 4 + 3] = acc_s[j].w;
            smem[o + 16 + j * 4 + 0] = acc_n[j].x; smem[o + 16 + j * 4 + 1] = acc_n[j].y;
            smem[o + 16 + j * 4 + 2] = acc_n[j].z; smem[o + 16 + j * 4 + 3] = acc_n[j].w;
        }
    }
    __syncthreads();
    if (grp == 0) {
        int o = t * 33;
        int col = cx * 4;
        float4 b4 = *reinterpret_cast<const float4*>(&bias[col]);
#pragma unroll
        for (int j = 0; j < 4; ++j) {
            acc_s[j].x += smem[o + j * 4 + 0]; acc_s[j].y += smem[o + j * 4 + 1];
            acc_s[j].z += smem[o + j * 4 + 2]; acc_s[j].w += smem[o + j * 4 + 3];
            acc_n[j].x += smem[o + 16 + j * 4 + 0]; acc_n[j].y += smem[o + 16 + j * 4 + 1];
            acc_n[j].z += smem[o + 16 + j * 4 + 2]; acc_n[j].w += smem[o + 16 + j * 4 + 3];
            int r = row0 + ry * 4 + j;
            if (r < M) {
                float4 sv;
                sv.x = acc_s[j].x + b4.x; sv.y = acc_s[j].y + b4.y;
                sv.z = acc_s[j].z + b4.z; sv.w = acc_s[j].w + b4.w;
                *reinterpret_cast<float4*>(&S[(size_t)r * DH + col]) = sv;
                ushort4 pk;
                pk.x = f2bf(acc_n[j].x); pk.y = f2bf(acc_n[j].y);
                pk.z = f2bf(acc_n[j].z); pk.w = f2bf(acc_n[j].w);
                *reinterpret_cast<ushort4*>(&P[(size_t)r * DH + col]) = pk;
            }
        }
    }
}

// ---- aggregation: src-bucket LDS slice, wave-per-(dst,bucket) row ----------
// grid = NSB * DTILES blocks x 1024 threads. LDS = 1250*64 bf16 = 160,000 B.
// ATOMIC-FREE: one writer per row -> plain coalesced 256B partial-plane store.
__global__ __launch_bounds__(1024) void agg_kernel(
    const unsigned short* __restrict__ P, const int* __restrict__ cnt8,
    const unsigned short* __restrict__ es16, float* __restrict__ Hn_part,
    int M, int npb8) {
    __shared__ __align__(16) unsigned short sP[MAXNPB * DH];
    int tid = threadIdx.x;
    int sb    = blockIdx.x & (NSB - 1);
    int dtile = blockIdx.x >> 3;
    int s0 = sb * npb8;
    int snodes = min(npb8, M - s0);

    // stage this bucket's P slice (coalesced uint4)
    {
        const uint4* gp = reinterpret_cast<const uint4*>(P + (size_t)s0 * DH);
        int cnt = snodes * 8;   // 128 B/node / 16 B
        for (int j = tid; j < cnt; j += 1024)
            *reinterpret_cast<uint4*>(&sP[j * 8]) = gp[j];
    }
    __syncthreads();

    int lane = tid & 63, wid = tid >> 6;
    int dpb  = (M + DTILES - 1) / DTILES;
    int d0t  = dtile * dpb;
    int dend = min(d0t + dpb, M);

    for (int dstn = d0t + wid; dstn < dend; dstn += 16) {
        int key = dstn * NSB + sb;
        int cnt = min(cnt8[key], CAP);
        if (cnt == 0) continue;
        size_t base = (size_t)key * CAP;
        float acc = 0.f;
        int cmax = cnt - 1;
        for (int e = 0; e < cnt; e += 4) {
            int i0 = es16[base + min(e + 0, cmax)];
            int i1 = es16[base + min(e + 1, cmax)];
            int i2 = es16[base + min(e + 2, cmax)];
            int i3 = es16[base + min(e + 3, cmax)];
            float m1 = (e + 1 < cnt) ? 1.f : 0.f;
            float m2 = (e + 2 < cnt) ? 1.f : 0.f;
            float m3 = (e + 3 < cnt) ? 1.f : 0.f;
            float f0 = bfu(sP[(size_t)i0 * DH + lane]);
            float f1 = bfu(sP[(size_t)i1 * DH + lane]);
            float f2 = bfu(sP[(size_t)i2 * DH + lane]);
            float f3 = bfu(sP[(size_t)i3 * DH + lane]);
            acc += f0;                       // e+0 always valid in-loop
            acc = fmaf(m1, f1, acc);
            acc = fmaf(m2, f2, acc);
            acc = fmaf(m3, f3, acc);
        }
        Hn_part[(size_t)key * DH + lane] = acc;   // plain coalesced 256 B
    }
}

// ---- fused finish + readout (last-block-done ticket) ----------------------
// finish: H = S + sum(partials)/deg (no relu) + per-graph register
// accumulation (graph_id sorted). Branchless 8-plane sum; fb=320.
__global__ __launch_bounds__(256) void finish_readout_kernel(
    const float* __restrict__ S, const float* __restrict__ Hn_part,
    const int* __restrict__ cnt8, const int* __restrict__ graph_id,
    float* __restrict__ H, float* __restrict__ gsum, float* __restrict__ gcnt,
    const float* __restrict__ Wc, const float* __restrict__ bc,
    float* __restrict__ out, float* __restrict__ out_feat,
    unsigned int* __restrict__ done, int M, int fb) {
    int tid  = threadIdx.x;
    int lane = tid & 63;
    int wv   = tid >> 6;
    {   // ---- finish work ----
        int wid = blockIdx.x * 4 + wv;
        int nw  = fb * 4;
        int cpw = (M + nw - 1) / nw;
        int n0 = wid * cpw, n1 = min(n0 + cpw, M);
        if (n0 < n1) {
            float acc = 0.f;
            int cnt = 0;
            int cur = graph_id[n0];
            for (int n = n0; n < n1; ++n) {
                int gid = graph_id[n];
                if (gid != cur) {
                    atomicAdd(&gsum[cur * DH + lane], acc);
                    if (lane == 0) atomicAdd(&gcnt[cur], (float)cnt);
                    acc = 0.f; cnt = 0; cur = gid;
                }
                const int4* cp = reinterpret_cast<const int4*>(&cnt8[n * NSB]);
                int4 c0 = cp[0], c1 = cp[1];
                int ca[8] = {c0.x, c0.y, c0.z, c0.w, c1.x, c1.y, c1.z, c1.w};
                int deg = ca[0] + ca[1] + ca[2] + ca[3] +
                          ca[4] + ca[5] + ca[6] + ca[7];
                // branchless: 8 unconditional parallel loads, then select
                float pv[8];
                size_t pb = (size_t)n * NSB * DH + lane;
#pragma unroll
                for (int b = 0; b < NSB; ++b) pv[b] = Hn_part[pb + b * DH];
                float hn = 0.f;
#pragma unroll
                for (int b = 0; b < NSB; ++b) hn += (ca[b] > 0) ? pv[b] : 0.f;
                float inv = 1.f / fmaxf((float)deg, 1.f);
                size_t o = (size_t)n * DH + lane;
                float val = fmaf(hn, inv, S[o]);
                H[o] = val;
                acc += val;
                ++cnt;
            }
            atomicAdd(&gsum[cur * DH + lane], acc);
            if (lane == 0) atomicAdd(&gcnt[cur], (float)cnt);
        }
    }

    // ---- last-block ticket ----
    __shared__ unsigned int s_ticket;
    __syncthreads();
    if (tid == 0) {
        __threadfence();   // release: publish this block's gsum/gcnt/H
        s_ticket = __hip_atomic_fetch_add(done, 1u, __ATOMIC_ACQ_REL,
                                          __HIP_MEMORY_SCOPE_AGENT);
    }
    __syncthreads();
    if (s_ticket != (unsigned int)(fb - 1)) return;
    if (tid == 0) __threadfence();   // acquire: see all blocks' gsum/gcnt
    __syncthreads();

    // ---- readout by the last block (256 threads, 4 entries each) ----
    __shared__ float ofs[NG][DH];
#pragma unroll
    for (int q = 0; q < 4; ++q) {
        int idx = tid + 256 * q;            // 0..1023 = (g,d)
        int g = idx >> 6, d = idx & 63;
        float of = gsum[idx] / fmaxf(gcnt[g], 1.0f);
        out_feat[idx] = of;
        ofs[g][d] = of;
    }
    __syncthreads();
    if (tid < NG * 2) {
        int gg = tid >> 1, cc = tid & 1;
        float accv = bc[cc];
#pragma unroll 8
        for (int dd = 0; dd < DH; ++dd) accv += ofs[gg][dd] * Wc[dd * 2 + cc];
        out[gg * 2 + cc] = accv;
    }
}

extern "C" void kernel_launch(void* const* d_in, const int* in_sizes, int n_in,
                              void* d_out, int out_size, void* d_ws, size_t ws_size,
                              hipStream_t stream) {
    const float* feat     = (const float*)d_in[0];
    const int*   src      = (const int*)d_in[1];
    const int*   dst      = (const int*)d_in[2];
    const int*   graph_id = (const int*)d_in[3];
    const float* Ws1 = (const float*)d_in[4];
    const float* Wn1 = (const float*)d_in[5];
    const float* b1  = (const float*)d_in[6];
    const float* Ws2 = (const float*)d_in[7];
    const float* Wn2 = (const float*)d_in[8];
    const float* b2  = (const float*)d_in[9];
    const float* Ws3 = (const float*)d_in[10];
    const float* Wn3 = (const float*)d_in[11];
    const float* b3  = (const float*)d_in[12];
    const float* Wc  = (const float*)d_in[13];
    const float* bc  = (const float*)d_in[14];

    const int M  = in_sizes[3];     // 10000 nodes
    const int E  = in_sizes[1];     // 320000 edges
    const int M2 = M * NSB;         // 80000 (dst,bucket) rows
    const int npb8 = (M + NSB - 1) / NSB;   // 1250 (<= MAXNPB)

    float* out      = (float*)d_out;             // 16 x 2
    float* out_feat = out + NG * 2;              // 16 x 64
    float* Hbuf     = out_feat + NG * DH;        // 10000 x 64 (final h)

    // workspace layout (256B-aligned carves)
    char* w = (char*)d_ws;
    size_t off = 0;
    auto carve = [&](size_t bytes) {
        size_t o = off;
        off = (off + bytes + 255) & ~(size_t)255;
        return o;
    };
    int*   cnt8  = (int*)  (w + carve((size_t)M2 * 4));
    float* gsum  = (float*)(w + carve((size_t)NG * DH * 4));
    float* gcnt  = (float*)(w + carve((size_t)NG * 4));
    unsigned int* done = (unsigned int*)(w + carve(4));
    size_t zero_bytes = off;                       // cnt8 + gsum + gcnt + done
    unsigned short* es16 = (unsigned short*)(w + carve((size_t)M2 * CAP * 2)); // 5.12 MB
    float* Sbuf  = (float*)(w + carve((size_t)M * DH * 4));
    unsigned short* Pbuf = (unsigned short*)(w + carve((size_t)M * DH * 2));
    float* Hn_part = (float*)(w + carve((size_t)M2 * DH * 4));   // 20.48 MB
    (void)ws_size; (void)n_in; (void)out_size;

    (void)hipMemsetAsync(d_ws, 0, zero_bytes, stream);

    int gb = (M + 63) / 64;          // 157 gemm blocks
    int eb = (E + 511) / 512;        // 625 build blocks (512 thr)
    int ab = NSB * DTILES;           // 256 agg blocks (1/CU)
    int fb = 320;                    // finish blocks: 1280 waves

    // layer 1 (K=256, split-K) + CSR build, ONE dispatch
    gemm1_build_kernel<<<gb + eb, 512, 0, stream>>>(
        feat, Ws1, Wn1, b1, Sbuf, Pbuf,
        src, dst, cnt8, es16, M, E, npb8, gb);
    agg_kernel<<<ab, 1024, 0, stream>>>(Pbuf, cnt8, es16, Hn_part, M, npb8);

    // layer 2 (K=64, split-kk): X = relu(S1 + sum(partials)/deg) fused;
    // in-place S is block-safe (each block reads only its own rows first)
    gemm_dual_kernel<<<gb, 512, 0, stream>>>(
        Sbuf, Ws2, Wn2, b2, Hn_part, cnt8, Sbuf, Pbuf, M);
    agg_kernel<<<ab, 1024, 0, stream>>>(Pbuf, cnt8, es16, Hn_part, M, npb8);

    // layer 3 (K=64, split-kk): X = relu(S2 + sum(partials)/deg) fused
    gemm_dual_kernel<<<gb, 512, 0, stream>>>(
        Sbuf, Ws3, Wn3, b3, Hn_part, cnt8, Sbuf, Pbuf, M);
    agg_kernel<<<ab, 1024, 0, stream>>>(Pbuf, cnt8, es16, Hn_part, M, npb8);

    // finish layer 3 + readout (fused via last-block-done ticket)
    finish_readout_kernel<<<fb, 256, 0, stream>>>(
        Sbuf, Hn_part, cnt8, graph_id, Hbuf, gsum, gcnt,
        Wc, bc, out, out_feat, done, M, fb);
}